// Round 12
// baseline (6573.125 us; speedup 1.0000x reference)
//
#include <hip/hip_runtime.h>

// ---------------------------------------------------------------------------
// BiGRU encoder, MI355X. Round 12 = round 11 with the sync protocol replaced
// by FLAGLESS, DRAINLESS sentinel dataflow:
//  - H buffers sentinel-initialized (0x7FFF bf16-NaN pairs; h always finite).
//  - Producer: 16B write-through h stores, NO vmcnt drain, NO flag stores.
//  - Consumer: af load IS the detection — sc0sc1 bypass dwordx4 loads,
//    per-frag sentinel validation, masked per-frag retries ("+v" keeps valid
//    lanes intact under divergent exec).
// Removes 2 of the 4 serial L3 legs per step (drain + flag->detect coupling).
//
// 64 blocks, 128 threads (2 waves), 1 block/CU.
//   wave A: gh = Whh(A,AGPR) x h(B) + gates + publish + out[].
//   wave B: gi = Wih x x + residual -> LDS FIFO (runs ahead, RD=4).
//
// ws layout:
//   Xb   [T][B][F] bf16      33,554,432 B
//   Hf   [T][B][F] bf16      33,554,432 B   (sentinel-init)
//   Hb   [T][B][F] bf16      33,554,432 B   (sentinel-init)
//   Wb   [2][2][1536][512]    6,291,456 B   (dir, src{0=Whh,1=Wih})
// ---------------------------------------------------------------------------

#define TT 2048
#define BB 16
#define FF 512
#define LL 10
#define RD 4
#define NTHR 128
#define SENT32 0x7FFF7FFF

typedef __attribute__((ext_vector_type(8))) short short8;
typedef __attribute__((ext_vector_type(4))) int   int4v;
typedef __attribute__((ext_vector_type(2))) int   int2v;
typedef __attribute__((ext_vector_type(4))) float f32x4;

// D = A*B + C with A (weights) pinned to AGPR, B (activations) in VGPR.
#define MFMA_WA(acc, wfa, afb) \
  asm("v_mfma_f32_16x16x32_bf16 %0, %1, %2, %0" : "+v"(acc) : "a"(wfa), "v"(afb))

__device__ __forceinline__ unsigned short f2bf(float f) {
  union { float f; unsigned int u; } v; v.f = f;
  unsigned int u = v.u;
  return (unsigned short)((u + 0x7fffu + ((u >> 16) & 1u)) >> 16);
}
__device__ __forceinline__ float bf2f(unsigned short h) {
  union { unsigned int u; float f; } v; v.u = ((unsigned int)h) << 16;
  return v.f;
}

__global__ void prep_x(const float* __restrict__ x, unsigned short* __restrict__ Xb) {
  int i = blockIdx.x * blockDim.x + threadIdx.x;
  int f = i & (FF - 1);
  int b = (i >> 9) & (BB - 1);
  int t = i >> 13;
  Xb[i] = f2bf(x[(size_t)b * (TT * 1025) + t * 1025 + f]);
}

__global__ void prep_w(const float* __restrict__ a, const float* __restrict__ b,
                       const float* __restrict__ c, const float* __restrict__ d,
                       unsigned short* __restrict__ Wb) {
  const int M = 1536 * 512;
  int i = blockIdx.x * blockDim.x + threadIdx.x;
  int m = i / M, r = i - m * M;
  const float* src = (m == 0) ? a : (m == 1) ? b : (m == 2) ? c : d;
  Wb[i] = f2bf(src[r]);
}

// sentinel-fill Hf+Hb (67,108,864 B = 4,194,304 uint4)
__global__ void prep_sent(uint4* __restrict__ H) {
  int i = blockIdx.x * blockDim.x + threadIdx.x;
  H[i] = make_uint4(SENT32, SENT32, SENT32, SENT32);
}

// ---------------------------------------------------------------------------
__global__ void __launch_bounds__(NTHR, 1) bigru_rec(
    const unsigned short* __restrict__ Xb,
    unsigned short* __restrict__ Hf, unsigned short* __restrict__ Hb,
    const unsigned short* __restrict__ Wb,
    const float* __restrict__ bih_f, const float* __restrict__ bhh_f,
    const float* __restrict__ bih_b, const float* __restrict__ bhh_b,
    float* __restrict__ out)
{
  const int bid  = blockIdx.x;
  const int d    = bid >> 5;           // direction
  const int j    = bid & 31;           // slice (16 hidden cols)
  const int tid  = threadIdx.x;
  const int w    = tid >> 6;           // 0 = gh wave, 1 = gi wave
  const int lane = tid & 63;
  const int l15  = lane & 15;          // batch row (D col after operand swap)
  const int hi   = lane >> 4;          // quarter: D rows hi*4+jj
  const int lk   = hi * 8;
  const int cb   = j * 16 + hi * 4;    // this lane's first out-col

  unsigned short* Hst = d ? Hb : Hf;
  const float* bih = d ? bih_b : bih_f;
  const float* bhh = d ? bhh_b : bhh_f;

  __shared__ float fifo[RD][64][17];   // B -> A : gi gates + residual x
  __shared__ int wrote_s, consumed_s;
  if (tid == 0) { wrote_s = 0; consumed_s = 0; }
  __syncthreads();

  // Weights: plain loads; used only via "a" MFMA constraint -> homed in AGPRs.
  const int src = w;                   // 0=Whh, 1=Wih
  int4v wf[3][16];
#pragma unroll
  for (int g = 0; g < 3; ++g) {
    const unsigned short* wrow =
        Wb + (size_t)((d * 2 + src) * 1536 + g * 512 + j * 16 + l15) * 512 + lk;
#pragma unroll
    for (int kk = 0; kk < 16; ++kk)
      wf[g][kk] = *(const int4v*)(wrow + kk * 32);
  }

  if (w == 0) {
    // ====================== WAVE A: gh + gates + publish ===================
    __builtin_amdgcn_s_setprio(1);
    const f32x4 bh0 = *(const f32x4*)(bhh + cb);
    const f32x4 bh1 = *(const f32x4*)(bhh + 512 + cb);
    const f32x4 bh2 = *(const f32x4*)(bhh + 1024 + cb);
    float hc[4] = {0.f, 0.f, 0.f, 0.f};   // carry: batch l15, cols cb+jj

    for (int t = 0; t < TT; ++t) {
      f32x4 a0 = {0,0,0,0}, a1 = {0,0,0,0}, a2 = {0,0,0,0},
            a3 = {0,0,0,0}, a4 = {0,0,0,0}, a5 = {0,0,0,0};
      if (t > 0) {
        // --- sentinel dataflow: the af load IS the detection -------------
        const unsigned short* Arow =
            Hst + (size_t)((t - 1) * BB + l15) * FF + lk;
        int4v af[16];
#pragma unroll
        for (int kk = 0; kk < 16; ++kk)
          asm volatile("global_load_dwordx4 %0, %1, off offset:%2 sc0 sc1"
                       : "=v"(af[kk]) : "v"(Arow), "i"(kk * 64));
        asm volatile("s_waitcnt vmcnt(0)" ::: "memory");
        __builtin_amdgcn_sched_barrier(0);
        unsigned bad = 0;
#pragma unroll
        for (int kk = 0; kk < 16; ++kk)
          if (af[kk][0] == (int)SENT32 || af[kk][3] == (int)SENT32)
            bad |= (1u << kk);
        while (__any((int)bad)) {
#pragma unroll
          for (int kk = 0; kk < 16; ++kk)
            if (bad & (1u << kk))
              asm volatile("global_load_dwordx4 %0, %1, off offset:%2 sc0 sc1"
                           : "+v"(af[kk]) : "v"(Arow), "i"(kk * 64));
          asm volatile("s_waitcnt vmcnt(0)" ::: "memory");
          __builtin_amdgcn_sched_barrier(0);
          bad = 0;
#pragma unroll
          for (int kk = 0; kk < 16; ++kk)
            if (af[kk][0] == (int)SENT32 || af[kk][3] == (int)SENT32)
              bad |= (1u << kk);
        }
        __builtin_amdgcn_sched_barrier(0);
#pragma unroll
        for (int kk = 0; kk < 16; kk += 2) {
          MFMA_WA(a0, wf[0][kk],     af[kk]);
          MFMA_WA(a2, wf[1][kk],     af[kk]);
          MFMA_WA(a4, wf[2][kk],     af[kk]);
          MFMA_WA(a1, wf[0][kk + 1], af[kk + 1]);
          MFMA_WA(a3, wf[1][kk + 1], af[kk + 1]);
          MFMA_WA(a5, wf[2][kk + 1], af[kk + 1]);
        }
        asm volatile("s_nop 7\n\ts_nop 7");  // MFMA D -> VALU hazard guard
      }
      const int slot = t & (RD - 1);
      while (__hip_atomic_load(&wrote_s, __ATOMIC_ACQUIRE,
                               __HIP_MEMORY_SCOPE_WORKGROUP) < t + 1) {}
      float fr[4], fz[4], fn[4], fx[4];
#pragma unroll
      for (int jj = 0; jj < 4; ++jj) {
        fr[jj] = fifo[slot][lane][jj];
        fz[jj] = fifo[slot][lane][4 + jj];
        fn[jj] = fifo[slot][lane][8 + jj];
        fx[jj] = fifo[slot][lane][12 + jj];
      }
      __hip_atomic_store(&consumed_s, t + 1, __ATOMIC_RELEASE,
                         __HIP_MEMORY_SCOPE_WORKGROUP);

      unsigned short us[4]; f32x4 h2v;
#pragma unroll
      for (int jj = 0; jj < 4; ++jj) {
        const float ghr = a0[jj] + a1[jj] + bh0[jj];
        const float ghz = a2[jj] + a3[jj] + bh1[jj];
        const float ghn = a4[jj] + a5[jj] + bh2[jj];
        const float rr = 1.f / (1.f + __expf(-(fr[jj] + ghr)));
        const float zz = 1.f / (1.f + __expf(-(fz[jj] + ghz)));
        const float ee = __expf(2.f * (fn[jj] + rr * ghn));
        const float nn = 1.f - 2.f / (ee + 1.f);        // tanh, inf-safe
        const float h2 = (1.f - zz) * nn + zz * hc[jj] + fx[jj];
        hc[jj] = h2; h2v[jj] = h2; us[jj] = f2bf(h2);
      }
      // --- h publish: fire-and-forget 16B write-through (no drain, no flag)
      const unsigned int dw0 = (unsigned int)us[0] | ((unsigned int)us[1] << 16);
      const unsigned int dw1 = (unsigned int)us[2] | ((unsigned int)us[3] << 16);
      const unsigned int p0 = (unsigned int)__shfl_xor((int)dw0, 16);
      const unsigned int p1 = (unsigned int)__shfl_xor((int)dw1, 16);
      if (!(hi & 1)) {
        int4v pk; pk[0] = (int)dw0; pk[1] = (int)dw1;
        pk[2] = (int)p0; pk[3] = (int)p1;
        unsigned short* wp =
            Hst + (size_t)(t * BB + l15) * FF + j * 16 + (hi >> 1) * 8;
        asm volatile("global_store_dwordx4 %0, %1, off sc0 sc1"
                     :: "v"(wp), "v"(pk) : "memory");
      }
      // out store (fire-and-forget): one dwordx4 per lane
      if (t >= LL && t < TT - LL) {
        float* op = out + ((size_t)l15 * (TT - 2 * LL) + (t - LL)) * 1024
                  + d * 512 + cb;
        *(f32x4*)op = h2v;
      }
    }
  } else {
    // ====================== WAVE B: gi + residual -> FIFO ==================
    const f32x4 bi0 = *(const f32x4*)(bih + cb);
    const f32x4 bi1 = *(const f32x4*)(bih + 512 + cb);
    const f32x4 bi2 = *(const f32x4*)(bih + 1024 + cb);
    for (int t = 0; t < TT; ++t) {
      const int slot = t & (RD - 1);
      while (t - __hip_atomic_load(&consumed_s, __ATOMIC_ACQUIRE,
                                   __HIP_MEMORY_SCOPE_WORKGROUP) >= RD) {}
      const int tx = d ? (TT - 1 - t) : t;
      const unsigned short* Arow = Xb + (size_t)(tx * BB + l15) * FF + lk;
      int4v af[16];
#pragma unroll
      for (int kk = 0; kk < 16; ++kk)
        af[kk] = *(const int4v*)(Arow + kk * 32);
      f32x4 a0 = {0,0,0,0}, a1 = {0,0,0,0}, a2 = {0,0,0,0},
            a3 = {0,0,0,0}, a4 = {0,0,0,0}, a5 = {0,0,0,0};
#pragma unroll
      for (int kk = 0; kk < 16; kk += 2) {
        MFMA_WA(a0, wf[0][kk],     af[kk]);
        MFMA_WA(a2, wf[1][kk],     af[kk]);
        MFMA_WA(a4, wf[2][kk],     af[kk]);
        MFMA_WA(a1, wf[0][kk + 1], af[kk + 1]);
        MFMA_WA(a3, wf[1][kk + 1], af[kk + 1]);
        MFMA_WA(a5, wf[2][kk + 1], af[kk + 1]);
      }
      asm volatile("s_nop 7\n\ts_nop 7");
      // residual x: 4 adjacent bf16 = one 8B load
      const int2v xw = *(const int2v*)(Xb + (size_t)(tx * BB + l15) * FF + cb);
      float xv[4];
      xv[0] = bf2f((unsigned short)(xw[0] & 0xffff));
      xv[1] = bf2f((unsigned short)((unsigned int)xw[0] >> 16));
      xv[2] = bf2f((unsigned short)(xw[1] & 0xffff));
      xv[3] = bf2f((unsigned short)((unsigned int)xw[1] >> 16));
#pragma unroll
      for (int jj = 0; jj < 4; ++jj) {
        fifo[slot][lane][jj]      = a0[jj] + a1[jj] + bi0[jj];
        fifo[slot][lane][4 + jj]  = a2[jj] + a3[jj] + bi1[jj];
        fifo[slot][lane][8 + jj]  = a4[jj] + a5[jj] + bi2[jj];
        fifo[slot][lane][12 + jj] = xv[jj];
      }
      __hip_atomic_store(&wrote_s, t + 1, __ATOMIC_RELEASE,
                         __HIP_MEMORY_SCOPE_WORKGROUP);
    }
  }
}

// ---------------------------------------------------------------------------
extern "C" void kernel_launch(void* const* d_in, const int* in_sizes, int n_in,
                              void* d_out, int out_size, void* d_ws, size_t ws_size,
                              hipStream_t stream) {
  const float* x     = (const float*)d_in[0];
  const float* Wih_f = (const float*)d_in[1];
  const float* Whh_f = (const float*)d_in[2];
  const float* bih_f = (const float*)d_in[3];
  const float* bhh_f = (const float*)d_in[4];
  const float* Wih_b = (const float*)d_in[5];
  const float* Whh_b = (const float*)d_in[6];
  const float* bih_b = (const float*)d_in[7];
  const float* bhh_b = (const float*)d_in[8];
  float* out = (float*)d_out;

  char* ws = (char*)d_ws;
  unsigned short* Xb = (unsigned short*)ws;
  unsigned short* Hf = (unsigned short*)(ws + (size_t)33554432);
  unsigned short* Hb = (unsigned short*)(ws + (size_t)2 * 33554432);
  unsigned short* Wb = (unsigned short*)(ws + (size_t)3 * 33554432);

  prep_x<<<65536, 256, 0, stream>>>(x, Xb);
  prep_w<<<12288, 256, 0, stream>>>(Whh_f, Wih_f, Whh_b, Wih_b, Wb);
  prep_sent<<<16384, 256, 0, stream>>>((uint4*)Hf);   // fills Hf AND Hb
  bigru_rec<<<64, NTHR, 0, stream>>>(Xb, Hf, Hb, Wb, bih_f, bhh_f, bih_b, bhh_b,
                                     out);
}

// Round 14
// 5708.414 us; speedup vs baseline: 1.1515x; 1.1515x over previous
//
#include <hip/hip_runtime.h>

// ---------------------------------------------------------------------------
// BiGRU encoder, MI355X. Round 14 = round 11 (proven, 5.53 ms) + two fixes:
//  1) BLOCK-MAJOR H [T][32][16][16]: producer's 512B step-output is 4 FULL
//     cache lines (was 16 scattered 32B pieces); consumer loads fully
//     coalesced. Writer: j*256 + l15*16 + (hi>>1)*8. Reader frag kk:
//     (t-1)*8192 + (hi>>1)*256 + l15*16 + (hi&1)*8 + kk*512.
//  2) PIPELINED 2-deep flag poll (vmcnt(1) sampling every ~100cy instead of
//     every RTT); out[] store moved before the drain so the poll queue is
//     clean; poll regs kept live until after vmcnt(0) (stale-load fence).
//
// 64 blocks, 128 threads (2 waves), 1 block/CU.
//   wave A: gh = Whh(A,AGPR) x h(B) + gates + h/out publish + flags.
//   wave B: gi = Wih x x + residual -> LDS FIFO (runs ahead, RD=4).
//
// ws layout:
//   Xb   [T][B][F] bf16      33,554,432 B
//   Hf   [T][32][16][16]     33,554,432 B
//   Hb   [T][32][16][16]     33,554,432 B
//   Wb   [2][2][1536][512]    6,291,456 B
//   flags 2 dirs x 4 replicas x 32 int
// ---------------------------------------------------------------------------

#define TT 2048
#define BB 16
#define FF 512
#define LL 10
#define RD 4
#define NTHR 128

typedef __attribute__((ext_vector_type(8))) short short8;
typedef __attribute__((ext_vector_type(4))) int   int4v;
typedef __attribute__((ext_vector_type(2))) int   int2v;
typedef __attribute__((ext_vector_type(4))) float f32x4;

// D = A*B + C with A (weights) pinned to AGPR, B (activations) in VGPR.
#define MFMA_WA(acc, wfa, afb) \
  asm("v_mfma_f32_16x16x32_bf16 %0, %1, %2, %0" : "+v"(acc) : "a"(wfa), "v"(afb))

__device__ __forceinline__ unsigned short f2bf(float f) {
  union { float f; unsigned int u; } v; v.f = f;
  unsigned int u = v.u;
  return (unsigned short)((u + 0x7fffu + ((u >> 16) & 1u)) >> 16);
}
__device__ __forceinline__ float bf2f(unsigned short h) {
  union { unsigned int u; float f; } v; v.u = ((unsigned int)h) << 16;
  return v.f;
}

__global__ void prep_x(const float* __restrict__ x, unsigned short* __restrict__ Xb) {
  int i = blockIdx.x * blockDim.x + threadIdx.x;
  int f = i & (FF - 1);
  int b = (i >> 9) & (BB - 1);
  int t = i >> 13;
  Xb[i] = f2bf(x[(size_t)b * (TT * 1025) + t * 1025 + f]);
}

__global__ void prep_w(const float* __restrict__ a, const float* __restrict__ b,
                       const float* __restrict__ c, const float* __restrict__ d,
                       unsigned short* __restrict__ Wb) {
  const int M = 1536 * 512;
  int i = blockIdx.x * blockDim.x + threadIdx.x;
  int m = i / M, r = i - m * M;
  const float* src = (m == 0) ? a : (m == 1) ? b : (m == 2) ? c : d;
  Wb[i] = f2bf(src[r]);
}

__global__ void prep_flags(int* __restrict__ flags) {
  int i = threadIdx.x;
  if (i < 256) flags[i] = 0;
}

// ---------------------------------------------------------------------------
__global__ void __launch_bounds__(NTHR, 1) bigru_rec(
    const unsigned short* __restrict__ Xb,
    unsigned short* __restrict__ Hf, unsigned short* __restrict__ Hb,
    const unsigned short* __restrict__ Wb,
    const float* __restrict__ bih_f, const float* __restrict__ bhh_f,
    const float* __restrict__ bih_b, const float* __restrict__ bhh_b,
    int* __restrict__ flags, float* __restrict__ out)
{
  const int bid  = blockIdx.x;
  const int d    = bid >> 5;           // direction
  const int j    = bid & 31;           // slice (16 hidden cols)
  const int tid  = threadIdx.x;
  const int w    = tid >> 6;           // 0 = gh wave, 1 = gi wave
  const int lane = tid & 63;
  const int l15  = lane & 15;          // batch row (D col, operand-swapped)
  const int hi   = lane >> 4;          // quarter: 4 adjacent out-cols
  const int lk   = hi * 8;
  const int cb   = j * 16 + hi * 4;    // this lane's first out-col

  unsigned short* Hst = d ? Hb : Hf;   // block-major [T][32][16][16]
  int* flg = flags + d * 128;          // 4 replica lines of 32 ints
  const float* bih = d ? bih_b : bih_f;
  const float* bhh = d ? bhh_b : bhh_f;

  __shared__ float fifo[RD][64][17];   // B -> A : gi gates + residual x
  __shared__ int wrote_s, consumed_s;
  if (tid == 0) { wrote_s = 0; consumed_s = 0; }
  __syncthreads();

  // Weights: plain loads; used only via "a" MFMA constraint -> homed in AGPRs.
  const int src = w;                   // 0=Whh, 1=Wih
  int4v wf[3][16];
#pragma unroll
  for (int g = 0; g < 3; ++g) {
    const unsigned short* wrow =
        Wb + (size_t)((d * 2 + src) * 1536 + g * 512 + j * 16 + l15) * 512 + lk;
#pragma unroll
    for (int kk = 0; kk < 16; ++kk)
      wf[g][kk] = *(const int4v*)(wrow + kk * 32);
  }

  if (w == 0) {
    // ====================== WAVE A: gh + gates + publish ===================
    __builtin_amdgcn_s_setprio(1);
    const f32x4 bh0 = *(const f32x4*)(bhh + cb);
    const f32x4 bh1 = *(const f32x4*)(bhh + 512 + cb);
    const f32x4 bh2 = *(const f32x4*)(bhh + 1024 + cb);
    float hc[4] = {0.f, 0.f, 0.f, 0.f};   // carry: batch l15, cols cb+jj
    int* myrep = flg + (j & 3) * 32;       // this consumer's flag replica line
    const int* fp = myrep + (lane & 31);   // one flag per lane (32-63 dup)

    for (int t = 0; t < TT; ++t) {
      f32x4 a0 = {0,0,0,0}, a1 = {0,0,0,0}, a2 = {0,0,0,0},
            a3 = {0,0,0,0}, a4 = {0,0,0,0}, a5 = {0,0,0,0};
      int v0 = t, v1 = t;                  // poll regs (live until drain)
      if (t > 0) {
        // --- pipelined 2-deep flag poll: sample every issue-gap, not RTT ---
        asm volatile("global_load_dword %0, %1, off sc0 sc1"
                     : "=v"(v0) : "v"(fp));
        for (;;) {
          asm volatile("global_load_dword %0, %1, off sc0 sc1"
                       : "=v"(v1) : "v"(fp));
          asm volatile("s_waitcnt vmcnt(1)" ::: "memory");
          if (__all(v0 >= t)) break;
          asm volatile("global_load_dword %0, %1, off sc0 sc1"
                       : "=v"(v0) : "v"(fp));
          asm volatile("s_waitcnt vmcnt(1)" ::: "memory");
          if (__all(v1 >= t)) break;
        }
        __builtin_amdgcn_sched_barrier(0);   // no load hoisting above the poll
        // block-major af frags: frag kk = h block 2kk+(hi>>1), col (hi&1)*8
        const unsigned short* Ab = Hst + (size_t)(t - 1) * 8192
                                 + (hi >> 1) * 256 + l15 * 16 + (hi & 1) * 8;
        int4v af[16];
#pragma unroll
        for (int kk = 0; kk < 16; ++kk)
          af[kk] = *(const int4v*)(Ab + kk * 512);
#pragma unroll
        for (int kk = 0; kk < 16; kk += 2) {
          MFMA_WA(a0, wf[0][kk],     af[kk]);
          MFMA_WA(a2, wf[1][kk],     af[kk]);
          MFMA_WA(a4, wf[2][kk],     af[kk]);
          MFMA_WA(a1, wf[0][kk + 1], af[kk + 1]);
          MFMA_WA(a3, wf[1][kk + 1], af[kk + 1]);
          MFMA_WA(a5, wf[2][kk + 1], af[kk + 1]);
        }
        asm volatile("s_nop 7\n\ts_nop 7");  // MFMA D -> VALU hazard guard
      }
      const int slot = t & (RD - 1);
      while (__hip_atomic_load(&wrote_s, __ATOMIC_ACQUIRE,
                               __HIP_MEMORY_SCOPE_WORKGROUP) < t + 1) {}
      float fr[4], fz[4], fn[4], fx[4];
#pragma unroll
      for (int jj = 0; jj < 4; ++jj) {
        fr[jj] = fifo[slot][lane][jj];
        fz[jj] = fifo[slot][lane][4 + jj];
        fn[jj] = fifo[slot][lane][8 + jj];
        fx[jj] = fifo[slot][lane][12 + jj];
      }
      __hip_atomic_store(&consumed_s, t + 1, __ATOMIC_RELEASE,
                         __HIP_MEMORY_SCOPE_WORKGROUP);

      unsigned short us[4]; f32x4 h2v;
#pragma unroll
      for (int jj = 0; jj < 4; ++jj) {
        const float ghr = a0[jj] + a1[jj] + bh0[jj];
        const float ghz = a2[jj] + a3[jj] + bh1[jj];
        const float ghn = a4[jj] + a5[jj] + bh2[jj];
        const float rr = 1.f / (1.f + __expf(-(fr[jj] + ghr)));
        const float zz = 1.f / (1.f + __expf(-(fz[jj] + ghz)));
        const float ee = __expf(2.f * (fn[jj] + rr * ghn));
        const float nn = 1.f - 2.f / (ee + 1.f);        // tanh, inf-safe
        const float h2 = (1.f - zz) * nn + zz * hc[jj] + fx[jj];
        hc[jj] = h2; h2v[jj] = h2; us[jj] = f2bf(h2);
      }
      // --- h publish: block-major, 4 FULL cache lines per block step ------
      const unsigned int dw0 = (unsigned int)us[0] | ((unsigned int)us[1] << 16);
      const unsigned int dw1 = (unsigned int)us[2] | ((unsigned int)us[3] << 16);
      const unsigned int p0 = (unsigned int)__shfl_xor((int)dw0, 16);
      const unsigned int p1 = (unsigned int)__shfl_xor((int)dw1, 16);
      if (!(hi & 1)) {
        int4v pk; pk[0] = (int)dw0; pk[1] = (int)dw1;
        pk[2] = (int)p0; pk[3] = (int)p1;
        unsigned short* wp = Hst + (size_t)t * 8192 + j * 256
                           + l15 * 16 + (hi >> 1) * 8;
        asm volatile("global_store_dwordx4 %0, %1, off sc0 sc1"
                     :: "v"(wp), "v"(pk) : "memory");
      }
      // out store BEFORE drain (plain store acks at L2, keeps poll queue clean)
      if (t >= LL && t < TT - LL) {
        float* op = out + ((size_t)l15 * (TT - 2 * LL) + (t - LL)) * 1024
                  + d * 512 + cb;
        *(f32x4*)op = h2v;
      }
      asm volatile("s_waitcnt vmcnt(0)" ::: "memory");   // h at coherence point
      asm volatile("" :: "v"(v0), "v"(v1));  // poll regs safe to reuse now
      if (lane == 0) {                 // publish to all 4 replica lines
#pragma unroll
        for (int r = 0; r < 4; ++r)
          __hip_atomic_store(flg + r * 32 + j, t + 1, __ATOMIC_RELAXED,
                             __HIP_MEMORY_SCOPE_AGENT);
      }
    }
  } else {
    // ====================== WAVE B: gi + residual -> FIFO ==================
    const f32x4 bi0 = *(const f32x4*)(bih + cb);
    const f32x4 bi1 = *(const f32x4*)(bih + 512 + cb);
    const f32x4 bi2 = *(const f32x4*)(bih + 1024 + cb);
    for (int t = 0; t < TT; ++t) {
      const int slot = t & (RD - 1);
      while (t - __hip_atomic_load(&consumed_s, __ATOMIC_ACQUIRE,
                                   __HIP_MEMORY_SCOPE_WORKGROUP) >= RD) {}
      const int tx = d ? (TT - 1 - t) : t;
      const unsigned short* Arow = Xb + (size_t)(tx * BB + l15) * FF + lk;
      int4v af[16];
#pragma unroll
      for (int kk = 0; kk < 16; ++kk)
        af[kk] = *(const int4v*)(Arow + kk * 32);
      f32x4 a0 = {0,0,0,0}, a1 = {0,0,0,0}, a2 = {0,0,0,0},
            a3 = {0,0,0,0}, a4 = {0,0,0,0}, a5 = {0,0,0,0};
#pragma unroll
      for (int kk = 0; kk < 16; kk += 2) {
        MFMA_WA(a0, wf[0][kk],     af[kk]);
        MFMA_WA(a2, wf[1][kk],     af[kk]);
        MFMA_WA(a4, wf[2][kk],     af[kk]);
        MFMA_WA(a1, wf[0][kk + 1], af[kk + 1]);
        MFMA_WA(a3, wf[1][kk + 1], af[kk + 1]);
        MFMA_WA(a5, wf[2][kk + 1], af[kk + 1]);
      }
      asm volatile("s_nop 7\n\ts_nop 7");
      // residual x: 4 adjacent bf16 = one 8B load
      const int2v xw = *(const int2v*)(Xb + (size_t)(tx * BB + l15) * FF + cb);
      float xv[4];
      xv[0] = bf2f((unsigned short)(xw[0] & 0xffff));
      xv[1] = bf2f((unsigned short)((unsigned int)xw[0] >> 16));
      xv[2] = bf2f((unsigned short)(xw[1] & 0xffff));
      xv[3] = bf2f((unsigned short)((unsigned int)xw[1] >> 16));
#pragma unroll
      for (int jj = 0; jj < 4; ++jj) {
        fifo[slot][lane][jj]      = a0[jj] + a1[jj] + bi0[jj];
        fifo[slot][lane][4 + jj]  = a2[jj] + a3[jj] + bi1[jj];
        fifo[slot][lane][8 + jj]  = a4[jj] + a5[jj] + bi2[jj];
        fifo[slot][lane][12 + jj] = xv[jj];
      }
      __hip_atomic_store(&wrote_s, t + 1, __ATOMIC_RELEASE,
                         __HIP_MEMORY_SCOPE_WORKGROUP);
    }
  }
}

// ---------------------------------------------------------------------------
extern "C" void kernel_launch(void* const* d_in, const int* in_sizes, int n_in,
                              void* d_out, int out_size, void* d_ws, size_t ws_size,
                              hipStream_t stream) {
  const float* x     = (const float*)d_in[0];
  const float* Wih_f = (const float*)d_in[1];
  const float* Whh_f = (const float*)d_in[2];
  const float* bih_f = (const float*)d_in[3];
  const float* bhh_f = (const float*)d_in[4];
  const float* Wih_b = (const float*)d_in[5];
  const float* Whh_b = (const float*)d_in[6];
  const float* bih_b = (const float*)d_in[7];
  const float* bhh_b = (const float*)d_in[8];
  float* out = (float*)d_out;

  char* ws = (char*)d_ws;
  unsigned short* Xb = (unsigned short*)ws;
  unsigned short* Hf = (unsigned short*)(ws + (size_t)33554432);
  unsigned short* Hb = (unsigned short*)(ws + (size_t)2 * 33554432);
  unsigned short* Wb = (unsigned short*)(ws + (size_t)3 * 33554432);
  int* flags         = (int*)(ws + (size_t)3 * 33554432 + 6291456);

  prep_x<<<65536, 256, 0, stream>>>(x, Xb);
  prep_w<<<12288, 256, 0, stream>>>(Whh_f, Wih_f, Whh_b, Wih_b, Wb);
  prep_flags<<<1, 256, 0, stream>>>(flags);
  bigru_rec<<<64, NTHR, 0, stream>>>(Xb, Hf, Hb, Wb, bih_f, bhh_f, bih_b, bhh_b,
                                     flags, out);
}